// Round 2
// baseline (312.265 us; speedup 1.0000x reference)
//
#include <hip/hip_runtime.h>
#include <hip/hip_bf16.h>
#include <cstdint>

// Problem constants
#define BB 2
#define SS 2048
#define DD 768
#define HH 12
#define DHH 64
#define DFF 3072
#define MM (BB * SS)   // 4096

typedef __attribute__((ext_vector_type(8))) short bf16x8;
typedef __attribute__((ext_vector_type(4))) float f32x4;
typedef __attribute__((ext_vector_type(4))) unsigned short u16x4;

#define DEV static __device__ __forceinline__

typedef __attribute__((address_space(1))) void AS1void;
typedef __attribute__((address_space(3))) void AS3void;

DEV void async_copy16(const void* g, void* l) {
  __builtin_amdgcn_global_load_lds((AS1void*)g, (AS3void*)l, 16, 0, 0);
}

DEV unsigned short bf16bits(float f) {
  __hip_bfloat16 h = __float2bfloat16(f);
  return *(unsigned short*)&h;
}

// ---------------- LayerNorm: fp32 [rows][768] -> bf16 ----------------
// one wave per row; 4 rows per block
__global__ __launch_bounds__(256) void ln_kernel(
    const float* __restrict__ x, const float* __restrict__ gain,
    const float* __restrict__ off, __hip_bfloat16* __restrict__ out)
{
  const int wave = threadIdx.x >> 6;
  const int lane = threadIdx.x & 63;
  const int row = blockIdx.x * 4 + wave;
  const float* xr = x + (size_t)row * DD;

  float4 v[3];
  float s1 = 0.f, s2 = 0.f;
#pragma unroll
  for (int j = 0; j < 3; ++j) {
    v[j] = *(const float4*)(xr + (j * 64 + lane) * 4);
    s1 += v[j].x + v[j].y + v[j].z + v[j].w;
    s2 += v[j].x * v[j].x + v[j].y * v[j].y + v[j].z * v[j].z + v[j].w * v[j].w;
  }
#pragma unroll
  for (int d = 1; d < 64; d <<= 1) {
    s1 += __shfl_xor(s1, d);
    s2 += __shfl_xor(s2, d);
  }
  const float mean = s1 * (1.0f / 768.0f);
  const float var = fmaxf(s2 * (1.0f / 768.0f) - mean * mean, 0.0f);
  const float rs = 1.0f / (sqrtf(var) + 1e-5f);   // matches ref: (x-m)/(std+1e-5)

  unsigned short* orow = (unsigned short*)out + (size_t)row * DD;
#pragma unroll
  for (int j = 0; j < 3; ++j) {
    const int c = (j * 64 + lane) * 4;
    float4 g4 = *(const float4*)(gain + c);
    float4 o4 = *(const float4*)(off + c);
    u16x4 pk;
    pk[0] = bf16bits(g4.x * ((v[j].x - mean) * rs) + o4.x);
    pk[1] = bf16bits(g4.y * ((v[j].y - mean) * rs) + o4.y);
    pk[2] = bf16bits(g4.z * ((v[j].z - mean) * rs) + o4.z);
    pk[3] = bf16bits(g4.w * ((v[j].w - mean) * rs) + o4.w);
    *(u16x4*)(orow + c) = pk;
  }
}

// ---------------- Transpose fp32 [R][C] -> bf16 [C][R] ----------------
__global__ __launch_bounds__(256) void transpose_generic(
    const float* __restrict__ in, __hip_bfloat16* __restrict__ out, int R, int C)
{
  __shared__ float tile[64][65];
  const int c0 = blockIdx.x * 64, r0 = blockIdx.y * 64;
  for (int i = threadIdx.x; i < 4096; i += 256) {
    int r = i >> 6, c = i & 63;
    tile[r][c] = in[(size_t)(r0 + r) * C + c0 + c];
  }
  __syncthreads();
  for (int i = threadIdx.x; i < 4096; i += 256) {
    int c = i >> 6, r = i & 63;
    out[(size_t)(c0 + c) * R + r0 + r] = __float2bfloat16(tile[r][c]);
  }
}

// Wq/Wk/Wv [H][D][DH] -> bf16 WqkvT [2304][768] (n' = part*768 + h*64 + kk, k = d)
__global__ __launch_bounds__(256) void transpose_qkv(
    const float* __restrict__ Wq, const float* __restrict__ Wk,
    const float* __restrict__ Wv, __hip_bfloat16* __restrict__ out)
{
  __shared__ float tile[64][65];
  const int z = blockIdx.z;
  const int p = z / HH, h = z - p * HH;
  const float* in = (p == 0 ? Wq : (p == 1 ? Wk : Wv)) + (size_t)h * DD * DHH;
  const int r0 = blockIdx.y * 64;   // d-tile
  for (int i = threadIdx.x; i < 4096; i += 256) {
    int r = i >> 6, c = i & 63;
    tile[r][c] = in[(size_t)(r0 + r) * DHH + c];
  }
  __syncthreads();
  for (int i = threadIdx.x; i < 4096; i += 256) {
    int c = i >> 6, r = i & 63;
    out[(size_t)(p * DD + h * DHH + c) * DD + r0 + r] = __float2bfloat16(tile[r][c]);
  }
}

// ---------------- GEMM: bf16 A[M,K] x bf16 BT[N,K] (+bias, relu, residual) ----------------
// 128x128 tile, BK=32, 4 waves (2x2), each wave 64x64 = 4x4 frags of 16x16x32 MFMA
template<bool RELU, bool OUT_BF16, bool HAS_RES>
__global__ __launch_bounds__(256) void gemm_bt(
    const __hip_bfloat16* __restrict__ A, const __hip_bfloat16* __restrict__ BT,
    const float* __restrict__ bias, const float* __restrict__ res,
    void* __restrict__ outp, int M, int N, int K)
{
  __shared__ __hip_bfloat16 Alds[128 * 32];
  __shared__ __hip_bfloat16 Blds[128 * 32];
  const int tid = threadIdx.x;
  const int wave = tid >> 6;
  const int lane = tid & 63;
  const int fr = lane & 15, fq = lane >> 4;
  const int wr = wave >> 1, wc = wave & 1;
  const int bm = blockIdx.y * 128, bn = blockIdx.x * 128;

  // staging: 256 threads x 16B; round0 = rows 0..63, round1 = rows 64..127
  const int srow = tid >> 2;
  const int scol = (tid & 3) * 8;
  const __hip_bfloat16* ag0 = A + (size_t)(bm + srow) * K + scol;
  const __hip_bfloat16* ag1 = A + (size_t)(bm + 64 + srow) * K + scol;
  const __hip_bfloat16* bg0 = BT + (size_t)(bn + srow) * K + scol;
  const __hip_bfloat16* bg1 = BT + (size_t)(bn + 64 + srow) * K + scol;
  __hip_bfloat16* la0 = Alds + wave * 512;          // HW writes lane*16B on top
  __hip_bfloat16* la1 = Alds + 2048 + wave * 512;
  __hip_bfloat16* lb0 = Blds + wave * 512;
  __hip_bfloat16* lb1 = Blds + 2048 + wave * 512;

  f32x4 acc[4][4] = {};

  for (int k0 = 0; k0 < K; k0 += 32) {
    async_copy16(ag0 + k0, la0);
    async_copy16(ag1 + k0, la1);
    async_copy16(bg0 + k0, lb0);
    async_copy16(bg1 + k0, lb1);
    __syncthreads();   // drains vmcnt -> tiles visible
    bf16x8 af[4], bfr[4];
#pragma unroll
    for (int i = 0; i < 4; ++i)
      af[i] = *(const bf16x8*)(Alds + (wr * 64 + i * 16 + fr) * 32 + fq * 8);
#pragma unroll
    for (int j = 0; j < 4; ++j)
      bfr[j] = *(const bf16x8*)(Blds + (wc * 64 + j * 16 + fr) * 32 + fq * 8);
#pragma unroll
    for (int i = 0; i < 4; ++i)
#pragma unroll
      for (int j = 0; j < 4; ++j)
        acc[i][j] = __builtin_amdgcn_mfma_f32_16x16x32_bf16(af[i], bfr[j], acc[i][j], 0, 0, 0);
    __syncthreads();   // all reads done before next stage overwrites
  }

  // epilogue: C/D layout col = lane&15, row = (lane>>4)*4 + r
#pragma unroll
  for (int j = 0; j < 4; ++j) {
    const int c = bn + wc * 64 + j * 16 + fr;
    const float bv = bias[c];
#pragma unroll
    for (int i = 0; i < 4; ++i) {
#pragma unroll
      for (int r = 0; r < 4; ++r) {
        const int rr = bm + wr * 64 + i * 16 + fq * 4 + r;
        float v = acc[i][j][r] + bv;
        if (RELU) v = fmaxf(v, 0.0f);
        if (HAS_RES) v += res[(size_t)rr * N + c];
        if (OUT_BF16) ((__hip_bfloat16*)outp)[(size_t)rr * N + c] = __float2bfloat16(v);
        else          ((float*)outp)[(size_t)rr * N + c] = v;
      }
    }
  }
}

// ---------------- Flash attention (causal), bf16 QKV in one buffer [M][2304] ----------------
// grid: (S/64, B*H); 4 waves; wave owns 16 Q rows; KV tiles of 64
__global__ __launch_bounds__(256) void attn_kernel(
    const __hip_bfloat16* __restrict__ qkv, __hip_bfloat16* __restrict__ outp)
{
  const int HD = 3 * DD;   // 2304
  const int bh = blockIdx.y;
  const int b = bh / HH, h = bh - b * HH;
  const int q0 = blockIdx.x * 64;
  const int tid = threadIdx.x, wave = tid >> 6, lane = tid & 63;
  const int fr = lane & 15, fq = lane >> 4;

  const size_t base = (size_t)b * SS * HD;
  const __hip_bfloat16* Qp = qkv + base + h * DHH;
  const __hip_bfloat16* Kp = qkv + base + DD + h * DHH;
  const __hip_bfloat16* Vp = qkv + base + 2 * DD + h * DHH;

  __shared__ __hip_bfloat16 Klds[64][72];   // +8 pad: conflict-free b128 reads
  __shared__ __hip_bfloat16 Vt[64][72];     // V transposed [dh][t]
  __shared__ __hip_bfloat16 Plds[4][16][72];

  bf16x8 qf[2];
  {
    const int qrow = q0 + wave * 16 + fr;
#pragma unroll
    for (int kk = 0; kk < 2; ++kk)
      qf[kk] = *(const bf16x8*)(Qp + (size_t)qrow * HD + kk * 32 + fq * 8);
  }

  f32x4 oacc[4] = {};
  float mrow[4] = {-1e30f, -1e30f, -1e30f, -1e30f};
  float lrow[4] = {0.f, 0.f, 0.f, 0.f};

  const int ntiles = blockIdx.x + 1;
  for (int t = 0; t < ntiles; ++t) {
    const int kv0 = t * 64;
    __syncthreads();   // prior reads of Klds/Vt/Plds done
    // stage K rows [64][64] (vectorized 16B)
#pragma unroll
    for (int rp = 0; rp < 2; ++rp) {
      const int row = (tid >> 3) + rp * 32;
      const int c8 = (tid & 7) * 8;
      *(bf16x8*)(&Klds[row][c8]) = *(const bf16x8*)(Kp + (size_t)(kv0 + row) * HD + c8);
    }
    // stage V transposed (coalesced reads, scattered LDS writes)
#pragma unroll
    for (int i = 0; i < 16; ++i) {
      const int idx = tid + i * 256;
      const int tr = idx >> 6, dc = idx & 63;
      Vt[dc][tr] = Vp[(size_t)(kv0 + tr) * HD + dc];
    }
    __syncthreads();

    // scores: S[16 q][64 t] per wave
    f32x4 s[4];
#pragma unroll
    for (int nj = 0; nj < 4; ++nj) {
      f32x4 a = {};
#pragma unroll
      for (int kk = 0; kk < 2; ++kk) {
        bf16x8 kf = *(const bf16x8*)(&Klds[nj * 16 + fr][kk * 32 + fq * 8]);
        a = __builtin_amdgcn_mfma_f32_16x16x32_bf16(qf[kk], kf, a, 0, 0, 0);
      }
      s[nj] = a;
    }
    // scale + causal mask; D layout: row=fq*4+r, col=nj*16+fr
    float mnew[4];
#pragma unroll
    for (int r = 0; r < 4; ++r) mnew[r] = mrow[r];
#pragma unroll
    for (int nj = 0; nj < 4; ++nj) {
      const int tcol = kv0 + nj * 16 + fr;
#pragma unroll
      for (int r = 0; r < 4; ++r) {
        const int qg = q0 + wave * 16 + fq * 4 + r;
        float v = s[nj][r] * 0.125f;
        v = (tcol <= qg) ? v : -1e30f;
        s[nj][r] = v;
        mnew[r] = fmaxf(mnew[r], v);
      }
    }
#pragma unroll
    for (int r = 0; r < 4; ++r)
#pragma unroll
      for (int d = 1; d < 16; d <<= 1)
        mnew[r] = fmaxf(mnew[r], __shfl_xor(mnew[r], d));

    float alpha[4], psum[4];
#pragma unroll
    for (int r = 0; r < 4; ++r) {
      alpha[r] = __expf(mrow[r] - mnew[r]);
      mrow[r] = mnew[r];
      psum[r] = 0.f;
    }
#pragma unroll
    for (int nj = 0; nj < 4; ++nj) {
#pragma unroll
      for (int r = 0; r < 4; ++r) {
        const float p = __expf(s[nj][r] - mnew[r]);
        psum[r] += p;
        Plds[wave][fq * 4 + r][nj * 16 + fr] = __float2bfloat16(p);
      }
    }
#pragma unroll
    for (int r = 0; r < 4; ++r) {
#pragma unroll
      for (int d = 1; d < 16; d <<= 1)
        psum[r] += __shfl_xor(psum[r], d);
      lrow[r] = lrow[r] * alpha[r] + psum[r];
    }
#pragma unroll
    for (int nj = 0; nj < 4; ++nj)
#pragma unroll
      for (int r = 0; r < 4; ++r)
        oacc[nj][r] *= alpha[r];
    __syncthreads();   // P visible (cross-lane within wave + uniform)

    // PV: O[16 q][64 dh] += P[16][64] * V[64][64]
#pragma unroll
    for (int nj = 0; nj < 4; ++nj) {
#pragma unroll
      for (int kk = 0; kk < 2; ++kk) {
        bf16x8 pf = *(const bf16x8*)(&Plds[wave][fr][kk * 32 + fq * 8]);
        bf16x8 vf = *(const bf16x8*)(&Vt[nj * 16 + fr][kk * 32 + fq * 8]);
        oacc[nj] = __builtin_amdgcn_mfma_f32_16x16x32_bf16(pf, vf, oacc[nj], 0, 0, 0);
      }
    }
  }

  // normalize + write concat output [M][768] bf16
#pragma unroll
  for (int nj = 0; nj < 4; ++nj) {
#pragma unroll
    for (int r = 0; r < 4; ++r) {
      const int qg = q0 + wave * 16 + fq * 4 + r;
      const float v = oacc[nj][r] / lrow[r];
      outp[(size_t)(b * SS + qg) * DD + h * DHH + nj * 16 + fr] = __float2bfloat16(v);
    }
  }
}

// ---------------- host ----------------
extern "C" void kernel_launch(void* const* d_in, const int* in_sizes, int n_in,
                              void* d_out, int out_size, void* d_ws, size_t ws_size,
                              hipStream_t stream)
{
  (void)in_sizes; (void)n_in; (void)out_size; (void)ws_size;
  const float* X  = (const float*)d_in[0];
  const float* Wq = (const float*)d_in[1];
  const float* bq = (const float*)d_in[2];
  const float* Wk = (const float*)d_in[3];
  const float* bk = (const float*)d_in[4];
  const float* Wv = (const float*)d_in[5];
  const float* bv = (const float*)d_in[6];
  const float* W0 = (const float*)d_in[7];
  const float* b0 = (const float*)d_in[8];
  const float* W1 = (const float*)d_in[9];
  const float* b1 = (const float*)d_in[10];
  const float* W2 = (const float*)d_in[11];
  const float* b2 = (const float*)d_in[12];
  const float* g1 = (const float*)d_in[13];
  const float* o1 = (const float*)d_in[14];
  const float* g2 = (const float*)d_in[15];
  const float* o2 = (const float*)d_in[16];

  char* ws = (char*)d_ws;
  auto alloc = [&](size_t bytes) {
    char* p = ws;
    ws += (bytes + 255) & ~(size_t)255;
    return p;
  };
  __hip_bfloat16* ln1    = (__hip_bfloat16*)alloc((size_t)MM * DD * 2);
  __hip_bfloat16* qkvb16 = (__hip_bfloat16*)alloc((size_t)MM * 3 * DD * 2);
  __hip_bfloat16* attnb  = (__hip_bfloat16*)alloc((size_t)MM * DD * 2);
  float*          hbuf   = (float*)alloc((size_t)MM * DD * 4);
  __hip_bfloat16* ln2    = (__hip_bfloat16*)alloc((size_t)MM * DD * 2);
  __hip_bfloat16* ffn1   = (__hip_bfloat16*)alloc((size_t)MM * DFF * 2);
  __hip_bfloat16* WqkvT  = (__hip_bfloat16*)alloc((size_t)3 * DD * DD * 2);
  __hip_bfloat16* W0T    = (__hip_bfloat16*)alloc((size_t)DD * DD * 2);
  __hip_bfloat16* W1T    = (__hip_bfloat16*)alloc((size_t)DFF * DD * 2);
  __hip_bfloat16* W2T    = (__hip_bfloat16*)alloc((size_t)DD * DFF * 2);
  float*          qkvbias= (float*)alloc((size_t)3 * DD * 4);

  // weight repack (bf16, transposed [N][K])
  transpose_qkv<<<dim3(1, 12, 36), 256, 0, stream>>>(Wq, Wk, Wv, WqkvT);
  transpose_generic<<<dim3(12, 12), 256, 0, stream>>>(W0, W0T, DD, DD);
  transpose_generic<<<dim3(48, 12), 256, 0, stream>>>(W1, W1T, DD, DFF);
  transpose_generic<<<dim3(12, 48), 256, 0, stream>>>(W2, W2T, DFF, DD);
  hipMemcpyAsync(qkvbias,          bq, DD * 4, hipMemcpyDeviceToDevice, stream);
  hipMemcpyAsync(qkvbias + DD,     bk, DD * 4, hipMemcpyDeviceToDevice, stream);
  hipMemcpyAsync(qkvbias + 2 * DD, bv, DD * 4, hipMemcpyDeviceToDevice, stream);

  // ln1(X) -> bf16
  ln_kernel<<<MM / 4, 256, 0, stream>>>(X, g1, o1, ln1);
  // QKV: [4096,768] x [2304,768]^T -> bf16 [4096,2304]
  gemm_bt<false, true, false><<<dim3(3 * DD / 128, MM / 128), 256, 0, stream>>>(
      ln1, WqkvT, qkvbias, nullptr, qkvb16, MM, 3 * DD, DD);
  // attention -> bf16 [4096,768]
  attn_kernel<<<dim3(SS / 64, BB * HH), 256, 0, stream>>>(qkvb16, attnb);
  // proj + X residual -> h fp32
  gemm_bt<false, false, true><<<dim3(DD / 128, MM / 128), 256, 0, stream>>>(
      attnb, W0T, b0, X, hbuf, MM, DD, DD);
  // ln2(h) -> bf16
  ln_kernel<<<MM / 4, 256, 0, stream>>>(hbuf, g2, o2, ln2);
  // ffn1 + relu -> bf16 [4096,3072]
  gemm_bt<true, true, false><<<dim3(DFF / 128, MM / 128), 256, 0, stream>>>(
      ln2, W1T, b1, nullptr, ffn1, MM, DFF, DD);
  // ffn2 + h residual -> d_out fp32
  gemm_bt<false, false, true><<<dim3(DD / 128, MM / 128), 256, 0, stream>>>(
      ffn1, W2T, b2, hbuf, (float*)d_out, MM, DD, DFF);
}

// Round 3
// 300.019 us; speedup vs baseline: 1.0408x; 1.0408x over previous
//
#include <hip/hip_runtime.h>
#include <hip/hip_bf16.h>
#include <cstdint>

// Problem constants
#define BB 2
#define SS 2048
#define DD 768
#define HH 12
#define DHH 64
#define DFF 3072
#define MM (BB * SS)   // 4096

typedef __attribute__((ext_vector_type(8))) short bf16x8;
typedef __attribute__((ext_vector_type(4))) float f32x4;
typedef __attribute__((ext_vector_type(16))) float f32x16;
typedef __attribute__((ext_vector_type(4))) unsigned short u16x4;
typedef unsigned int u32;

#define DEV static __device__ __forceinline__

typedef __attribute__((address_space(1))) void AS1void;
typedef __attribute__((address_space(3))) void AS3void;

DEV void async_copy16(const void* g, void* l) {
  __builtin_amdgcn_global_load_lds((AS1void*)g, (AS3void*)l, 16, 0, 0);
}

DEV unsigned short bf16bits(float f) {
  __hip_bfloat16 h = __float2bfloat16(f);
  return *(unsigned short*)&h;
}

DEV u32 pack2(float a, float b) {
  return ((u32)bf16bits(b) << 16) | (u32)bf16bits(a);
}

// ---------------- LayerNorm: fp32 [rows][768] -> bf16 ----------------
__global__ __launch_bounds__(256) void ln_kernel(
    const float* __restrict__ x, const float* __restrict__ gain,
    const float* __restrict__ off, __hip_bfloat16* __restrict__ out)
{
  const int wave = threadIdx.x >> 6;
  const int lane = threadIdx.x & 63;
  const int row = blockIdx.x * 4 + wave;
  const float* xr = x + (size_t)row * DD;

  float4 v[3];
  float s1 = 0.f, s2 = 0.f;
#pragma unroll
  for (int j = 0; j < 3; ++j) {
    v[j] = *(const float4*)(xr + (j * 64 + lane) * 4);
    s1 += v[j].x + v[j].y + v[j].z + v[j].w;
    s2 += v[j].x * v[j].x + v[j].y * v[j].y + v[j].z * v[j].z + v[j].w * v[j].w;
  }
#pragma unroll
  for (int d = 1; d < 64; d <<= 1) {
    s1 += __shfl_xor(s1, d);
    s2 += __shfl_xor(s2, d);
  }
  const float mean = s1 * (1.0f / 768.0f);
  const float var = fmaxf(s2 * (1.0f / 768.0f) - mean * mean, 0.0f);
  const float rs = 1.0f / (sqrtf(var) + 1e-5f);

  unsigned short* orow = (unsigned short*)out + (size_t)row * DD;
#pragma unroll
  for (int j = 0; j < 3; ++j) {
    const int c = (j * 64 + lane) * 4;
    float4 g4 = *(const float4*)(gain + c);
    float4 o4 = *(const float4*)(off + c);
    u16x4 pk;
    pk[0] = bf16bits(g4.x * ((v[j].x - mean) * rs) + o4.x);
    pk[1] = bf16bits(g4.y * ((v[j].y - mean) * rs) + o4.y);
    pk[2] = bf16bits(g4.z * ((v[j].z - mean) * rs) + o4.z);
    pk[3] = bf16bits(g4.w * ((v[j].w - mean) * rs) + o4.w);
    *(u16x4*)(orow + c) = pk;
  }
}

// ---------------- Transpose fp32 [R][C] -> bf16 [C][R] ----------------
__global__ __launch_bounds__(256) void transpose_generic(
    const float* __restrict__ in, __hip_bfloat16* __restrict__ out, int R, int C)
{
  __shared__ float tile[64][65];
  const int c0 = blockIdx.x * 64, r0 = blockIdx.y * 64;
  for (int i = threadIdx.x; i < 4096; i += 256) {
    int r = i >> 6, c = i & 63;
    tile[r][c] = in[(size_t)(r0 + r) * C + c0 + c];
  }
  __syncthreads();
  for (int i = threadIdx.x; i < 4096; i += 256) {
    int c = i >> 6, r = i & 63;
    out[(size_t)(c0 + c) * R + r0 + r] = __float2bfloat16(tile[r][c]);
  }
}

// Wq/Wk/Wv [H][D][DH] -> bf16 WqkvT [2304][768]
__global__ __launch_bounds__(256) void transpose_qkv(
    const float* __restrict__ Wq, const float* __restrict__ Wk,
    const float* __restrict__ Wv, __hip_bfloat16* __restrict__ out)
{
  __shared__ float tile[64][65];
  const int z = blockIdx.z;
  const int p = z / HH, h = z - p * HH;
  const float* in = (p == 0 ? Wq : (p == 1 ? Wk : Wv)) + (size_t)h * DD * DHH;
  const int r0 = blockIdx.y * 64;
  for (int i = threadIdx.x; i < 4096; i += 256) {
    int r = i >> 6, c = i & 63;
    tile[r][c] = in[(size_t)(r0 + r) * DHH + c];
  }
  __syncthreads();
  for (int i = threadIdx.x; i < 4096; i += 256) {
    int c = i >> 6, r = i & 63;
    out[(size_t)(p * DD + h * DHH + c) * DD + r0 + r] = __float2bfloat16(tile[r][c]);
  }
}

// ---------------- GEMM: bf16 A[M,K] x bf16 BT[N,K] ----------------
template<bool RELU, bool OUT_BF16, bool HAS_RES>
__global__ __launch_bounds__(256) void gemm_bt(
    const __hip_bfloat16* __restrict__ A, const __hip_bfloat16* __restrict__ BT,
    const float* __restrict__ bias, const float* __restrict__ res,
    void* __restrict__ outp, int M, int N, int K)
{
  __shared__ __hip_bfloat16 Alds[128 * 32];
  __shared__ __hip_bfloat16 Blds[128 * 32];
  const int tid = threadIdx.x;
  const int wave = tid >> 6;
  const int lane = tid & 63;
  const int fr = lane & 15, fq = lane >> 4;
  const int wr = wave >> 1, wc = wave & 1;
  const int bm = blockIdx.y * 128, bn = blockIdx.x * 128;

  const int srow = tid >> 2;
  const int scol = (tid & 3) * 8;
  const __hip_bfloat16* ag0 = A + (size_t)(bm + srow) * K + scol;
  const __hip_bfloat16* ag1 = A + (size_t)(bm + 64 + srow) * K + scol;
  const __hip_bfloat16* bg0 = BT + (size_t)(bn + srow) * K + scol;
  const __hip_bfloat16* bg1 = BT + (size_t)(bn + 64 + srow) * K + scol;
  __hip_bfloat16* la0 = Alds + wave * 512;
  __hip_bfloat16* la1 = Alds + 2048 + wave * 512;
  __hip_bfloat16* lb0 = Blds + wave * 512;
  __hip_bfloat16* lb1 = Blds + 2048 + wave * 512;

  f32x4 acc[4][4] = {};

  for (int k0 = 0; k0 < K; k0 += 32) {
    async_copy16(ag0 + k0, la0);
    async_copy16(ag1 + k0, la1);
    async_copy16(bg0 + k0, lb0);
    async_copy16(bg1 + k0, lb1);
    __syncthreads();
    bf16x8 af[4], bfr[4];
#pragma unroll
    for (int i = 0; i < 4; ++i)
      af[i] = *(const bf16x8*)(Alds + (wr * 64 + i * 16 + fr) * 32 + fq * 8);
#pragma unroll
    for (int j = 0; j < 4; ++j)
      bfr[j] = *(const bf16x8*)(Blds + (wc * 64 + j * 16 + fr) * 32 + fq * 8);
#pragma unroll
    for (int i = 0; i < 4; ++i)
#pragma unroll
      for (int j = 0; j < 4; ++j)
        acc[i][j] = __builtin_amdgcn_mfma_f32_16x16x32_bf16(af[i], bfr[j], acc[i][j], 0, 0, 0);
    __syncthreads();
  }

#pragma unroll
  for (int j = 0; j < 4; ++j) {
    const int c = bn + wc * 64 + j * 16 + fr;
    const float bv = bias[c];
#pragma unroll
    for (int i = 0; i < 4; ++i) {
#pragma unroll
      for (int r = 0; r < 4; ++r) {
        const int rr = bm + wr * 64 + i * 16 + fq * 4 + r;
        float v = acc[i][j][r] + bv;
        if (RELU) v = fmaxf(v, 0.0f);
        if (HAS_RES) v += res[(size_t)rr * N + c];
        if (OUT_BF16) ((__hip_bfloat16*)outp)[(size_t)rr * N + c] = __float2bfloat16(v);
        else          ((float*)outp)[(size_t)rr * N + c] = v;
      }
    }
  }
}

// ---------------- Flash attention, swapped-QK^T 32x32 structure ----------------
// grid: (S/128, B*H); 4 warps x 32 q-rows; KV tiles of 64.
// Per lane: q = wq0 + (lane&31); lanes l, l+32 hold complementary t-halves.
// K/Q fragments load direct from global (L2-resident); V staged transposed in
// LDS with XOR swizzle ((d&7)<<4 on byte addr, 128B row stride).
__global__ __launch_bounds__(256) void attn_kernel(
    const __hip_bfloat16* __restrict__ qkv, __hip_bfloat16* __restrict__ outp)
{
  const int HD = 3 * DD;   // 2304
  const int bh = blockIdx.y;
  const int b = bh / HH, h = bh - b * HH;
  const int bx = (int)gridDim.x - 1 - (int)blockIdx.x;   // heavy blocks first
  const int bq0 = bx * 128;
  const int tid = threadIdx.x, w = tid >> 6, lane = tid & 63;
  const int col = lane & 31, hi = lane >> 5;
  const int wq0 = bq0 + w * 32;
  const int qg = wq0 + col;

  const size_t base = (size_t)b * SS * HD;
  const __hip_bfloat16* Qp = qkv + base + h * DHH;
  const __hip_bfloat16* Kp = qkv + base + DD + h * DHH;
  const unsigned short* Vus = (const unsigned short*)(qkv + base + 2 * DD + h * DHH);

  __shared__ __align__(16) char Vt[8192];   // Vt[d=64][t=64] bf16, swizzled

  // Q fragments: lane holds Q row q=qg, k = kc*16 + hi*8 + e
  bf16x8 qf[4];
#pragma unroll
  for (int kc = 0; kc < 4; ++kc)
    qf[kc] = *(const bf16x8*)(Qp + (size_t)qg * HD + kc * 16 + hi * 8);

  f32x16 o0 = {}, o1 = {};
  float mreg = -1e30f, lreg = 0.f;
  const float CS = 0.125f * 1.44269504f;   // (1/sqrt(64)) * log2(e)

  // V staging addresses: thread owns column d=tid&63, t-rows [w*16, w*16+16)
  const int sd = tid & 63;
  const int stb = (tid >> 6) * 16;
  char* wv0 = &Vt[(sd * 128 + stb * 2) ^ ((sd & 7) << 4)];
  char* wv1 = &Vt[(sd * 128 + (stb + 8) * 2) ^ ((sd & 7) << 4)];

  const int ntiles = bq0 / 64 + 2;
  for (int t = 0; t < ntiles; ++t) {
    const int kv0 = t * 64;
    __syncthreads();   // all PV reads of previous tile done
    {
      const unsigned short* vrow = Vus + (size_t)(kv0 + stb) * HD + sd;
      union { unsigned short u[8]; bf16x8 v; } va, vb;
#pragma unroll
      for (int j = 0; j < 8; ++j) va.u[j] = vrow[(size_t)j * HD];
#pragma unroll
      for (int j = 0; j < 8; ++j) vb.u[j] = vrow[(size_t)(8 + j) * HD];
      *(bf16x8*)wv0 = va.v;
      *(bf16x8*)wv1 = vb.v;
    }
    __syncthreads();   // Vt ready

    if (kv0 <= wq0 + 31) {
      // ---- QK^T (swapped): St = K Q^T ; D col = q (lane-local) ----
      f32x16 s0 = {}, s1 = {};
      const __hip_bfloat16* krow0 = Kp + (size_t)(kv0 + col) * HD + hi * 8;
      const __hip_bfloat16* krow1 = Kp + (size_t)(kv0 + 32 + col) * HD + hi * 8;
#pragma unroll
      for (int kc = 0; kc < 4; ++kc) {
        bf16x8 k0 = *(const bf16x8*)(krow0 + kc * 16);
        bf16x8 k1 = *(const bf16x8*)(krow1 + kc * 16);
        s0 = __builtin_amdgcn_mfma_f32_32x32x16_bf16(k0, qf[kc], s0, 0, 0, 0);
        s1 = __builtin_amdgcn_mfma_f32_32x32x16_bf16(k1, qf[kc], s1, 0, 0, 0);
      }
      // ---- causal mask (diagonal tiles only; warp-uniform branch) ----
      if (kv0 + 63 > wq0) {
#pragma unroll
        for (int r = 0; r < 16; ++r) {
          const int tl = (r & 3) + 8 * (r >> 2) + 4 * hi;
          s0[r] = (kv0 + tl <= qg) ? s0[r] : -1e30f;
          s1[r] = (kv0 + 32 + tl <= qg) ? s1[r] : -1e30f;
        }
      }
      // ---- online softmax, fully in-register ----
      float mx = s0[0];
#pragma unroll
      for (int r = 1; r < 16; ++r) mx = fmaxf(mx, s0[r]);
#pragma unroll
      for (int r = 0; r < 16; ++r) mx = fmaxf(mx, s1[r]);
      mx = fmaxf(mx, __shfl_xor(mx, 32));
      const float mnew = fmaxf(mreg, mx);
      const float alpha = exp2f((mreg - mnew) * CS);
      mreg = mnew;
      const float mc = mnew * CS;
      float ps = 0.f;
#pragma unroll
      for (int r = 0; r < 16; ++r) {
        const float p0 = exp2f(s0[r] * CS - mc); s0[r] = p0; ps += p0;
        const float p1 = exp2f(s1[r] * CS - mc); s1[r] = p1; ps += p1;
      }
      ps += __shfl_xor(ps, 32);
      lreg = lreg * alpha + ps;
#pragma unroll
      for (int r = 0; r < 16; ++r) { o0[r] *= alpha; o1[r] *= alpha; }

      // ---- pack P rows to bf16 pairs; quad qd covers t = m*32 + 8qd + 4hi + {0..3} ----
      u32 pk0[4][2], pk1[4][2];
#pragma unroll
      for (int qd = 0; qd < 4; ++qd) {
        pk0[qd][0] = pack2(s0[4 * qd + 0], s0[4 * qd + 1]);
        pk0[qd][1] = pack2(s0[4 * qd + 2], s0[4 * qd + 3]);
        pk1[qd][0] = pack2(s1[4 * qd + 0], s1[4 * qd + 1]);
        pk1[qd][1] = pack2(s1[4 * qd + 2], s1[4 * qd + 3]);
      }
      // ---- PV: O += mfma(Vt-frag (A), P-frag (B)); O col = q stays lane-local ----
#pragma unroll
      for (int kc = 0; kc < 4; ++kc) {
        const int qa = 2 * (kc & 1), qb = qa + 1;
        const u32 A0 = (kc < 2) ? pk0[qa][0] : pk1[qa][0];
        const u32 A1 = (kc < 2) ? pk0[qa][1] : pk1[qa][1];
        const u32 B0 = (kc < 2) ? pk0[qb][0] : pk1[qb][0];
        const u32 B1 = (kc < 2) ? pk0[qb][1] : pk1[qb][1];
        const u32 send0 = hi ? A0 : B0;           // lo lanes send qb, hi lanes send qa
        const u32 send1 = hi ? A1 : B1;
        const u32 recv0 = __shfl_xor(send0, 32);
        const u32 recv1 = __shfl_xor(send1, 32);
        const u32 su0 = hi ? B0 : A0;
        const u32 su1 = hi ? B1 : A1;
        union { u32 u[4]; bf16x8 v; } pf;
        pf.u[0] = hi ? recv0 : su0;
        pf.u[1] = hi ? recv1 : su1;
        pf.u[2] = hi ? su0 : recv0;
        pf.u[3] = hi ? su1 : recv1;
        const int toff2 = (kc * 16 + hi * 8) * 2;
        const int d0 = col, d1 = 32 + col;
        bf16x8 vfa = *(const bf16x8*)&Vt[(d0 * 128 + toff2) ^ ((d0 & 7) << 4)];
        bf16x8 vfb = *(const bf16x8*)&Vt[(d1 * 128 + toff2) ^ ((d1 & 7) << 4)];
        o0 = __builtin_amdgcn_mfma_f32_32x32x16_bf16(vfa, pf.v, o0, 0, 0, 0);
        o1 = __builtin_amdgcn_mfma_f32_32x32x16_bf16(vfb, pf.v, o1, 0, 0, 0);
      }
    }
  }

  // ---- epilogue: O reg r -> d = (r&3) + 8*(r>>2) + 4*hi (+32 for o1) ----
  const float inv = 1.0f / lreg;
  unsigned short* orow = (unsigned short*)outp + ((size_t)(b * SS + wq0 + col)) * DD + h * DHH;
#pragma unroll
  for (int j = 0; j < 4; ++j) {
    u16x4 w4;
#pragma unroll
    for (int e = 0; e < 4; ++e) w4[e] = bf16bits(o0[4 * j + e] * inv);
    *(u16x4*)(orow + 8 * j + 4 * hi) = w4;
#pragma unroll
    for (int e = 0; e < 4; ++e) w4[e] = bf16bits(o1[4 * j + e] * inv);
    *(u16x4*)(orow + 32 + 8 * j + 4 * hi) = w4;
  }
}

// ---------------- host ----------------
extern "C" void kernel_launch(void* const* d_in, const int* in_sizes, int n_in,
                              void* d_out, int out_size, void* d_ws, size_t ws_size,
                              hipStream_t stream)
{
  (void)in_sizes; (void)n_in; (void)out_size; (void)ws_size;
  const float* X  = (const float*)d_in[0];
  const float* Wq = (const float*)d_in[1];
  const float* bq = (const float*)d_in[2];
  const float* Wk = (const float*)d_in[3];
  const float* bk = (const float*)d_in[4];
  const float* Wv = (const float*)d_in[5];
  const float* bv = (const float*)d_in[6];
  const float* W0 = (const float*)d_in[7];
  const float* b0 = (const float*)d_in[8];
  const float* W1 = (const float*)d_in[9];
  const float* b1 = (const float*)d_in[10];
  const float* W2 = (const float*)d_in[11];
  const float* b2 = (const float*)d_in[12];
  const float* g1 = (const float*)d_in[13];
  const float* o1 = (const float*)d_in[14];
  const float* g2 = (const float*)d_in[15];
  const float* o2 = (const float*)d_in[16];

  char* ws = (char*)d_ws;
  auto alloc = [&](size_t bytes) {
    char* p = ws;
    ws += (bytes + 255) & ~(size_t)255;
    return p;
  };
  __hip_bfloat16* ln1    = (__hip_bfloat16*)alloc((size_t)MM * DD * 2);
  __hip_bfloat16* qkvb16 = (__hip_bfloat16*)alloc((size_t)MM * 3 * DD * 2);
  __hip_bfloat16* attnb  = (__hip_bfloat16*)alloc((size_t)MM * DD * 2);
  float*          hbuf   = (float*)alloc((size_t)MM * DD * 4);
  __hip_bfloat16* ln2    = (__hip_bfloat16*)alloc((size_t)MM * DD * 2);
  __hip_bfloat16* ffn1   = (__hip_bfloat16*)alloc((size_t)MM * DFF * 2);
  __hip_bfloat16* WqkvT  = (__hip_bfloat16*)alloc((size_t)3 * DD * DD * 2);
  __hip_bfloat16* W0T    = (__hip_bfloat16*)alloc((size_t)DD * DD * 2);
  __hip_bfloat16* W1T    = (__hip_bfloat16*)alloc((size_t)DFF * DD * 2);
  __hip_bfloat16* W2T    = (__hip_bfloat16*)alloc((size_t)DD * DFF * 2);
  float*          qkvbias= (float*)alloc((size_t)3 * DD * 4);

  transpose_qkv<<<dim3(1, 12, 36), 256, 0, stream>>>(Wq, Wk, Wv, WqkvT);
  transpose_generic<<<dim3(12, 12), 256, 0, stream>>>(W0, W0T, DD, DD);
  transpose_generic<<<dim3(48, 12), 256, 0, stream>>>(W1, W1T, DD, DFF);
  transpose_generic<<<dim3(12, 48), 256, 0, stream>>>(W2, W2T, DFF, DD);
  hipMemcpyAsync(qkvbias,          bq, DD * 4, hipMemcpyDeviceToDevice, stream);
  hipMemcpyAsync(qkvbias + DD,     bk, DD * 4, hipMemcpyDeviceToDevice, stream);
  hipMemcpyAsync(qkvbias + 2 * DD, bv, DD * 4, hipMemcpyDeviceToDevice, stream);

  ln_kernel<<<MM / 4, 256, 0, stream>>>(X, g1, o1, ln1);
  gemm_bt<false, true, false><<<dim3(3 * DD / 128, MM / 128), 256, 0, stream>>>(
      ln1, WqkvT, qkvbias, nullptr, qkvb16, MM, 3 * DD, DD);
  attn_kernel<<<dim3(SS / 128, BB * HH), 256, 0, stream>>>(qkvb16, attnb);
  gemm_bt<false, false, true><<<dim3(DD / 128, MM / 128), 256, 0, stream>>>(
      attnb, W0T, b0, X, hbuf, MM, DD, DD);
  ln_kernel<<<MM / 4, 256, 0, stream>>>(hbuf, g2, o2, ln2);
  gemm_bt<true, true, false><<<dim3(DFF / 128, MM / 128), 256, 0, stream>>>(
      ln2, W1T, b1, nullptr, ffn1, MM, DFF, DD);
  gemm_bt<false, false, true><<<dim3(DD / 128, MM / 128), 256, 0, stream>>>(
      ffn1, W2T, b2, hbuf, (float*)d_out, MM, DD, DFF);
}

// Round 4
// 288.400 us; speedup vs baseline: 1.0828x; 1.0403x over previous
//
#include <hip/hip_runtime.h>
#include <hip/hip_bf16.h>
#include <cstdint>

// Problem constants
#define BB 2
#define SS 2048
#define DD 768
#define HH 12
#define DHH 64
#define DFF 3072
#define MM (BB * SS)   // 4096

typedef __attribute__((ext_vector_type(8))) short bf16x8;
typedef __attribute__((ext_vector_type(4))) float f32x4;
typedef __attribute__((ext_vector_type(16))) float f32x16;
typedef __attribute__((ext_vector_type(4))) unsigned short u16x4;
typedef __attribute__((ext_vector_type(8))) unsigned short u16x8;
typedef unsigned int u32;

#define DEV static __device__ __forceinline__

typedef __attribute__((address_space(1))) void AS1void;
typedef __attribute__((address_space(3))) void AS3void;

DEV void async_copy16(const void* g, void* l) {
  __builtin_amdgcn_global_load_lds((AS1void*)g, (AS3void*)l, 16, 0, 0);
}

DEV unsigned short bf16bits(float f) {
  __hip_bfloat16 h = __float2bfloat16(f);
  return *(unsigned short*)&h;
}

DEV u32 pack2(float a, float b) {
  return ((u32)bf16bits(b) << 16) | (u32)bf16bits(a);
}

// ---------------- LayerNorm: fp32 [rows][768] -> bf16 ----------------
__global__ __launch_bounds__(256) void ln_kernel(
    const float* __restrict__ x, const float* __restrict__ gain,
    const float* __restrict__ off, __hip_bfloat16* __restrict__ out)
{
  const int wave = threadIdx.x >> 6;
  const int lane = threadIdx.x & 63;
  const int row = blockIdx.x * 4 + wave;
  const float* xr = x + (size_t)row * DD;

  float4 v[3];
  float s1 = 0.f, s2 = 0.f;
#pragma unroll
  for (int j = 0; j < 3; ++j) {
    v[j] = *(const float4*)(xr + (j * 64 + lane) * 4);
    s1 += v[j].x + v[j].y + v[j].z + v[j].w;
    s2 += v[j].x * v[j].x + v[j].y * v[j].y + v[j].z * v[j].z + v[j].w * v[j].w;
  }
#pragma unroll
  for (int d = 1; d < 64; d <<= 1) {
    s1 += __shfl_xor(s1, d);
    s2 += __shfl_xor(s2, d);
  }
  const float mean = s1 * (1.0f / 768.0f);
  const float var = fmaxf(s2 * (1.0f / 768.0f) - mean * mean, 0.0f);
  const float rs = 1.0f / (sqrtf(var) + 1e-5f);

  unsigned short* orow = (unsigned short*)out + (size_t)row * DD;
#pragma unroll
  for (int j = 0; j < 3; ++j) {
    const int c = (j * 64 + lane) * 4;
    float4 g4 = *(const float4*)(gain + c);
    float4 o4 = *(const float4*)(off + c);
    u16x4 pk;
    pk[0] = bf16bits(g4.x * ((v[j].x - mean) * rs) + o4.x);
    pk[1] = bf16bits(g4.y * ((v[j].y - mean) * rs) + o4.y);
    pk[2] = bf16bits(g4.z * ((v[j].z - mean) * rs) + o4.z);
    pk[3] = bf16bits(g4.w * ((v[j].w - mean) * rs) + o4.w);
    *(u16x4*)(orow + c) = pk;
  }
}

// ---------------- Transpose fp32 [R][C] -> bf16 [C][R] ----------------
__global__ __launch_bounds__(256) void transpose_generic(
    const float* __restrict__ in, __hip_bfloat16* __restrict__ out, int R, int C)
{
  __shared__ float tile[64][65];
  const int c0 = blockIdx.x * 64, r0 = blockIdx.y * 64;
  for (int i = threadIdx.x; i < 4096; i += 256) {
    int r = i >> 6, c = i & 63;
    tile[r][c] = in[(size_t)(r0 + r) * C + c0 + c];
  }
  __syncthreads();
  for (int i = threadIdx.x; i < 4096; i += 256) {
    int c = i >> 6, r = i & 63;
    out[(size_t)(c0 + c) * R + r0 + r] = __float2bfloat16(tile[r][c]);
  }
}

// Wq/Wk/Wv [H][D][DH] -> bf16 WqkvT [2304][768]
__global__ __launch_bounds__(256) void transpose_qkv(
    const float* __restrict__ Wq, const float* __restrict__ Wk,
    const float* __restrict__ Wv, __hip_bfloat16* __restrict__ out)
{
  __shared__ float tile[64][65];
  const int z = blockIdx.z;
  const int p = z / HH, h = z - p * HH;
  const float* in = (p == 0 ? Wq : (p == 1 ? Wk : Wv)) + (size_t)h * DD * DHH;
  const int r0 = blockIdx.y * 64;
  for (int i = threadIdx.x; i < 4096; i += 256) {
    int r = i >> 6, c = i & 63;
    tile[r][c] = in[(size_t)(r0 + r) * DHH + c];
  }
  __syncthreads();
  for (int i = threadIdx.x; i < 4096; i += 256) {
    int c = i >> 6, r = i & 63;
    out[(size_t)(p * DD + h * DHH + c) * DD + r0 + r] = __float2bfloat16(tile[r][c]);
  }
}

// ---------------- GEMM: bf16 A[M,K] x bf16 BT[N,K] ----------------
template<bool RELU, bool OUT_BF16, bool HAS_RES>
__global__ __launch_bounds__(256) void gemm_bt(
    const __hip_bfloat16* __restrict__ A, const __hip_bfloat16* __restrict__ BT,
    const float* __restrict__ bias, const float* __restrict__ res,
    void* __restrict__ outp, int M, int N, int K)
{
  __shared__ __hip_bfloat16 Alds[128 * 32];
  __shared__ __hip_bfloat16 Blds[128 * 32];
  const int tid = threadIdx.x;
  const int wave = tid >> 6;
  const int lane = tid & 63;
  const int fr = lane & 15, fq = lane >> 4;
  const int wr = wave >> 1, wc = wave & 1;
  const int bm = blockIdx.y * 128, bn = blockIdx.x * 128;

  const int srow = tid >> 2;
  const int scol = (tid & 3) * 8;
  const __hip_bfloat16* ag0 = A + (size_t)(bm + srow) * K + scol;
  const __hip_bfloat16* ag1 = A + (size_t)(bm + 64 + srow) * K + scol;
  const __hip_bfloat16* bg0 = BT + (size_t)(bn + srow) * K + scol;
  const __hip_bfloat16* bg1 = BT + (size_t)(bn + 64 + srow) * K + scol;
  __hip_bfloat16* la0 = Alds + wave * 512;
  __hip_bfloat16* la1 = Alds + 2048 + wave * 512;
  __hip_bfloat16* lb0 = Blds + wave * 512;
  __hip_bfloat16* lb1 = Blds + 2048 + wave * 512;

  f32x4 acc[4][4] = {};

  for (int k0 = 0; k0 < K; k0 += 32) {
    async_copy16(ag0 + k0, la0);
    async_copy16(ag1 + k0, la1);
    async_copy16(bg0 + k0, lb0);
    async_copy16(bg1 + k0, lb1);
    __syncthreads();
    bf16x8 af[4], bfr[4];
#pragma unroll
    for (int i = 0; i < 4; ++i)
      af[i] = *(const bf16x8*)(Alds + (wr * 64 + i * 16 + fr) * 32 + fq * 8);
#pragma unroll
    for (int j = 0; j < 4; ++j)
      bfr[j] = *(const bf16x8*)(Blds + (wc * 64 + j * 16 + fr) * 32 + fq * 8);
#pragma unroll
    for (int i = 0; i < 4; ++i)
#pragma unroll
      for (int j = 0; j < 4; ++j)
        acc[i][j] = __builtin_amdgcn_mfma_f32_16x16x32_bf16(af[i], bfr[j], acc[i][j], 0, 0, 0);
    __syncthreads();
  }

#pragma unroll
  for (int j = 0; j < 4; ++j) {
    const int c = bn + wc * 64 + j * 16 + fr;
    const float bv = bias[c];
#pragma unroll
    for (int i = 0; i < 4; ++i) {
#pragma unroll
      for (int r = 0; r < 4; ++r) {
        const int rr = bm + wr * 64 + i * 16 + fq * 4 + r;
        float v = acc[i][j][r] + bv;
        if (RELU) v = fmaxf(v, 0.0f);
        if (HAS_RES) v += res[(size_t)rr * N + c];
        if (OUT_BF16) ((__hip_bfloat16*)outp)[(size_t)rr * N + c] = __float2bfloat16(v);
        else          ((float*)outp)[(size_t)rr * N + c] = v;
      }
    }
  }
}

// ---------------- Flash attention, swapped-QK^T 32x32, in-block KV-split ----------------
// grid: (S/32 = 64, B*H); block = 256 = 4 warps, ALL on the same 32-row q-strip.
// Warp w processes KV tiles t = 4j + w (interleaved), keeping private partial
// (m, l, O). Rounds of 4 tiles: cooperative V staging (4 x 8KB swizzled Vt
// buffers), 2 barriers per round. Epilogue: LSE-combine of the 4 partials via
// LDS (reuses the Vt space). K/Q load direct from global (L2-resident).
__global__ __launch_bounds__(256) void attn_kernel(
    const __hip_bfloat16* __restrict__ qkv, __hip_bfloat16* __restrict__ outp)
{
  const int HD = 3 * DD;   // 2304
  const int bh = blockIdx.y;
  const int b = bh / HH, h = bh - b * HH;
  const int bx = (int)gridDim.x - 1 - (int)blockIdx.x;   // heavy strips first
  const int q0 = bx * 32;
  const int tid = threadIdx.x, w = tid >> 6, lane = tid & 63;
  const int col = lane & 31, hi = lane >> 5;
  const int qg = q0 + col;

  const size_t base = (size_t)b * SS * HD;
  const __hip_bfloat16* Qp = qkv + base + h * DHH;
  const __hip_bfloat16* Kp = qkv + base + DD + h * DHH;
  const unsigned short* Vus = (const unsigned short*)(qkv + base + 2 * DD + h * DHH);

  // LDS: main loop = 4 x 8KB Vt buffers; epilogue reuses as opart[4][32][65] f32
  // (33280B) + ml[4][2][32] f32 (1024B).
  __shared__ __align__(16) char sm[34816];

  // Q fragments: lane holds Q row q=qg, k = kc*16 + hi*8 + e
  bf16x8 qf[4];
#pragma unroll
  for (int kc = 0; kc < 4; ++kc)
    qf[kc] = *(const bf16x8*)(Qp + (size_t)qg * HD + kc * 16 + hi * 8);

  f32x16 o0 = {}, o1 = {};
  float mreg = -1e30f, lreg = 0.f;
  const float CS = 0.125f * 1.44269504f;   // (1/sqrt(64)) * log2(e)

  // V staging: thread owns column d=tid&63, t-rows [stb, stb+16)
  const int sd = tid & 63;
  const int stb = (tid >> 6) * 16;
  const int swz0 = (sd * 128 + stb * 2) ^ ((sd & 7) << 4);
  const int swz1 = (sd * 128 + (stb + 8) * 2) ^ ((sd & 7) << 4);

  const int ntiles = ((q0 + 31) >> 6) + 1;
  const int nrounds = (ntiles + 3) >> 2;
  char* const vt_w = sm + w * 8192;

  for (int j = 0; j < nrounds; ++j) {
    __syncthreads();   // all PV reads of previous round done
    // ---- cooperative stage: tiles 4j+tt -> buffer tt ----
#pragma unroll
    for (int tt = 0; tt < 4; ++tt) {
      const int tw = 4 * j + tt;
      if (tw < ntiles) {
        const unsigned short* vrow = Vus + (size_t)(tw * 64 + stb) * HD + sd;
        union { unsigned short u[8]; bf16x8 v; } va, vb;
#pragma unroll
        for (int e = 0; e < 8; ++e) va.u[e] = vrow[(size_t)e * HD];
#pragma unroll
        for (int e = 0; e < 8; ++e) vb.u[e] = vrow[(size_t)(8 + e) * HD];
        char* bufb = sm + tt * 8192;
        *(bf16x8*)(bufb + swz0) = va.v;
        *(bf16x8*)(bufb + swz1) = vb.v;
      }
    }
    __syncthreads();   // Vt buffers ready

    const int tw = 4 * j + w;
    if (tw < ntiles) {
      const int kv0 = tw * 64;
      // ---- QK^T (swapped): St = K Q^T ; D col = q (lane-local) ----
      f32x16 s0 = {}, s1 = {};
      const __hip_bfloat16* krow0 = Kp + (size_t)(kv0 + col) * HD + hi * 8;
      const __hip_bfloat16* krow1 = Kp + (size_t)(kv0 + 32 + col) * HD + hi * 8;
#pragma unroll
      for (int kc = 0; kc < 4; ++kc) {
        bf16x8 k0 = *(const bf16x8*)(krow0 + kc * 16);
        bf16x8 k1 = *(const bf16x8*)(krow1 + kc * 16);
        s0 = __builtin_amdgcn_mfma_f32_32x32x16_bf16(k0, qf[kc], s0, 0, 0, 0);
        s1 = __builtin_amdgcn_mfma_f32_32x32x16_bf16(k1, qf[kc], s1, 0, 0, 0);
      }
      // ---- causal mask (last tile only; warp-uniform branch) ----
      if (kv0 + 63 > q0) {
#pragma unroll
        for (int r = 0; r < 16; ++r) {
          const int tl = (r & 3) + 8 * (r >> 2) + 4 * hi;
          s0[r] = (kv0 + tl <= qg) ? s0[r] : -1e30f;
          s1[r] = (kv0 + 32 + tl <= qg) ? s1[r] : -1e30f;
        }
      }
      // ---- online softmax, fully in-register ----
      float mx = s0[0];
#pragma unroll
      for (int r = 1; r < 16; ++r) mx = fmaxf(mx, s0[r]);
#pragma unroll
      for (int r = 0; r < 16; ++r) mx = fmaxf(mx, s1[r]);
      mx = fmaxf(mx, __shfl_xor(mx, 32));
      const float mnew = fmaxf(mreg, mx);
      const float alpha = exp2f((mreg - mnew) * CS);
      mreg = mnew;
      const float mc = mnew * CS;
      float ps = 0.f;
#pragma unroll
      for (int r = 0; r < 16; ++r) {
        const float p0 = exp2f(s0[r] * CS - mc); s0[r] = p0; ps += p0;
        const float p1 = exp2f(s1[r] * CS - mc); s1[r] = p1; ps += p1;
      }
      ps += __shfl_xor(ps, 32);
      lreg = lreg * alpha + ps;
#pragma unroll
      for (int r = 0; r < 16; ++r) { o0[r] *= alpha; o1[r] *= alpha; }

      // ---- pack P rows to bf16 pairs ----
      u32 pk0[4][2], pk1[4][2];
#pragma unroll
      for (int qd = 0; qd < 4; ++qd) {
        pk0[qd][0] = pack2(s0[4 * qd + 0], s0[4 * qd + 1]);
        pk0[qd][1] = pack2(s0[4 * qd + 2], s0[4 * qd + 3]);
        pk1[qd][0] = pack2(s1[4 * qd + 0], s1[4 * qd + 1]);
        pk1[qd][1] = pack2(s1[4 * qd + 2], s1[4 * qd + 3]);
      }
      // ---- PV: O += mfma(Vt-frag (A), P-frag (B)) ----
#pragma unroll
      for (int kc = 0; kc < 4; ++kc) {
        const int qa = 2 * (kc & 1), qb = qa + 1;
        const u32 A0 = (kc < 2) ? pk0[qa][0] : pk1[qa][0];
        const u32 A1 = (kc < 2) ? pk0[qa][1] : pk1[qa][1];
        const u32 B0 = (kc < 2) ? pk0[qb][0] : pk1[qb][0];
        const u32 B1 = (kc < 2) ? pk0[qb][1] : pk1[qb][1];
        const u32 send0 = hi ? A0 : B0;
        const u32 send1 = hi ? A1 : B1;
        const u32 recv0 = __shfl_xor(send0, 32);
        const u32 recv1 = __shfl_xor(send1, 32);
        const u32 su0 = hi ? B0 : A0;
        const u32 su1 = hi ? B1 : A1;
        union { u32 u[4]; bf16x8 v; } pf;
        pf.u[0] = hi ? recv0 : su0;
        pf.u[1] = hi ? recv1 : su1;
        pf.u[2] = hi ? su0 : recv0;
        pf.u[3] = hi ? su1 : recv1;
        const int toff2 = (kc * 16 + hi * 8) * 2;
        const int d0 = col, d1 = 32 + col;
        bf16x8 vfa = *(const bf16x8*)&vt_w[(d0 * 128 + toff2) ^ ((d0 & 7) << 4)];
        bf16x8 vfb = *(const bf16x8*)&vt_w[(d1 * 128 + toff2) ^ ((d1 & 7) << 4)];
        o0 = __builtin_amdgcn_mfma_f32_32x32x16_bf16(vfa, pf.v, o0, 0, 0, 0);
        o1 = __builtin_amdgcn_mfma_f32_32x32x16_bf16(vfb, pf.v, o1, 0, 0, 0);
      }
    }
  }

  // ---- combine the 4 warp-partials (flash-decode style) ----
  __syncthreads();   // all PV reads done; safe to overwrite sm
  float* opart = (float*)sm;                 // [4][32][65]
  float* mlp   = (float*)(sm + 33280);       // [w][0][q]=m, [w][1][q]=l
#pragma unroll
  for (int r = 0; r < 16; ++r) {
    const int d = (r & 3) + 8 * (r >> 2) + 4 * hi;
    opart[(w * 32 + col) * 65 + d]      = o0[r];
    opart[(w * 32 + col) * 65 + d + 32] = o1[r];
  }
  if (hi == 0) {
    mlp[w * 64 + col]      = mreg;
    mlp[w * 64 + 32 + col] = lreg;
  }
  __syncthreads();

  const int q = tid >> 3;
  const int e8 = (tid & 7) * 8;
  float mcv[4], lcv[4];
#pragma unroll
  for (int c = 0; c < 4; ++c) {
    mcv[c] = mlp[c * 64 + q];
    lcv[c] = mlp[c * 64 + 32 + q];
  }
  float mstar = fmaxf(fmaxf(mcv[0], mcv[1]), fmaxf(mcv[2], mcv[3]));
  float av[4], lstar = 0.f;
#pragma unroll
  for (int c = 0; c < 4; ++c) {
    av[c] = exp2f((mcv[c] - mstar) * CS);
    lstar += av[c] * lcv[c];
  }
  const float inv = 1.0f / lstar;
  float acc[8] = {};
#pragma unroll
  for (int c = 0; c < 4; ++c) {
    const float a = av[c];
#pragma unroll
    for (int e = 0; e < 8; ++e)
      acc[e] += a * opart[(c * 32 + q) * 65 + e8 + e];
  }
  u16x8 w8;
#pragma unroll
  for (int e = 0; e < 8; ++e) w8[e] = bf16bits(acc[e] * inv);
  unsigned short* orow = (unsigned short*)outp + (size_t)(b * SS + q0 + q) * DD + h * DHH + e8;
  *(u16x8*)orow = w8;
}

// ---------------- host ----------------
extern "C" void kernel_launch(void* const* d_in, const int* in_sizes, int n_in,
                              void* d_out, int out_size, void* d_ws, size_t ws_size,
                              hipStream_t stream)
{
  (void)in_sizes; (void)n_in; (void)out_size; (void)ws_size;
  const float* X  = (const float*)d_in[0];
  const float* Wq = (const float*)d_in[1];
  const float* bq = (const float*)d_in[2];
  const float* Wk = (const float*)d_in[3];
  const float* bk = (const float*)d_in[4];
  const float* Wv = (const float*)d_in[5];
  const float* bv = (const float*)d_in[6];
  const float* W0 = (const float*)d_in[7];
  const float* b0 = (const float*)d_in[8];
  const float* W1 = (const float*)d_in[9];
  const float* b1 = (const float*)d_in[10];
  const float* W2 = (const float*)d_in[11];
  const float* b2 = (const float*)d_in[12];
  const float* g1 = (const float*)d_in[13];
  const float* o1 = (const float*)d_in[14];
  const float* g2 = (const float*)d_in[15];
  const float* o2 = (const float*)d_in[16];

  char* ws = (char*)d_ws;
  auto alloc = [&](size_t bytes) {
    char* p = ws;
    ws += (bytes + 255) & ~(size_t)255;
    return p;
  };
  __hip_bfloat16* ln1    = (__hip_bfloat16*)alloc((size_t)MM * DD * 2);
  __hip_bfloat16* qkvb16 = (__hip_bfloat16*)alloc((size_t)MM * 3 * DD * 2);
  __hip_bfloat16* attnb  = (__hip_bfloat16*)alloc((size_t)MM * DD * 2);
  float*          hbuf   = (float*)alloc((size_t)MM * DD * 4);
  __hip_bfloat16* ln2    = (__hip_bfloat16*)alloc((size_t)MM * DD * 2);
  __hip_bfloat16* ffn1   = (__hip_bfloat16*)alloc((size_t)MM * DFF * 2);
  __hip_bfloat16* WqkvT  = (__hip_bfloat16*)alloc((size_t)3 * DD * DD * 2);
  __hip_bfloat16* W0T    = (__hip_bfloat16*)alloc((size_t)DD * DD * 2);
  __hip_bfloat16* W1T    = (__hip_bfloat16*)alloc((size_t)DFF * DD * 2);
  __hip_bfloat16* W2T    = (__hip_bfloat16*)alloc((size_t)DD * DFF * 2);
  float*          qkvbias= (float*)alloc((size_t)3 * DD * 4);

  transpose_qkv<<<dim3(1, 12, 36), 256, 0, stream>>>(Wq, Wk, Wv, WqkvT);
  transpose_generic<<<dim3(12, 12), 256, 0, stream>>>(W0, W0T, DD, DD);
  transpose_generic<<<dim3(48, 12), 256, 0, stream>>>(W1, W1T, DD, DFF);
  transpose_generic<<<dim3(12, 48), 256, 0, stream>>>(W2, W2T, DFF, DD);
  hipMemcpyAsync(qkvbias,          bq, DD * 4, hipMemcpyDeviceToDevice, stream);
  hipMemcpyAsync(qkvbias + DD,     bk, DD * 4, hipMemcpyDeviceToDevice, stream);
  hipMemcpyAsync(qkvbias + 2 * DD, bv, DD * 4, hipMemcpyDeviceToDevice, stream);

  ln_kernel<<<MM / 4, 256, 0, stream>>>(X, g1, o1, ln1);
  gemm_bt<false, true, false><<<dim3(3 * DD / 128, MM / 128), 256, 0, stream>>>(
      ln1, WqkvT, qkvbias, nullptr, qkvb16, MM, 3 * DD, DD);
  attn_kernel<<<dim3(SS / 32, BB * HH), 256, 0, stream>>>(qkvb16, attnb);
  gemm_bt<false, false, true><<<dim3(DD / 128, MM / 128), 256, 0, stream>>>(
      attnb, W0T, b0, X, hbuf, MM, DD, DD);
  ln_kernel<<<MM / 4, 256, 0, stream>>>(hbuf, g2, o2, ln2);
  gemm_bt<true, true, false><<<dim3(DFF / 128, MM / 128), 256, 0, stream>>>(
      ln2, W1T, b1, nullptr, ffn1, MM, DFF, DD);
  gemm_bt<false, false, true><<<dim3(DD / 128, MM / 128), 256, 0, stream>>>(
      ffn1, W2T, b2, hbuf, (float*)d_out, MM, DD, DFF);
}